// Round 3
// baseline (157.492 us; speedup 1.0000x reference)
//
#include <hip/hip_runtime.h>
#include <hip/hip_bf16.h>

// Problem constants
#define K_DIM 4096
#define N_DIM 14336
#define M_DIM 256
#define BN 32
#define BK 64
#define NITER 64        // K_DIM / BK
#define RS 80           // wb row stride in shorts (160 B: 16B-aligned rows, <=2-way banks)

typedef __attribute__((ext_vector_type(4))) float f32x4;
typedef __attribute__((ext_vector_type(8))) short short8;

__device__ __forceinline__ unsigned short f2bf(float f) {
    union { float f; unsigned u; } v; v.f = f;
    unsigned r = v.u + 0x7fffu + ((v.u >> 16) & 1u);   // RNE
    return (unsigned short)(r >> 16);
}

__device__ __forceinline__ void glds16(const void* g, void* l) {
    __builtin_amdgcn_global_load_lds(
        (const __attribute__((address_space(1))) void*)g,
        (__attribute__((address_space(3))) void*)l, 16, 0, 0);
}

// Pre-convert x (fp32 [256][4096]) into bf16 MFMA-A-fragment order:
// chunk = ktile*16 + mtile (ktile=k/32, mtile=m/16); lane l of chunk holds
// 8 bf16 = x[mtile*16 + (l&15)][ktile*32 + (l>>4)*8 .. +8]. One K-tile of
// BK=64 (2 ktiles) = 32 chunks = 32 KB CONTIGUOUS -> global_load_lds linear.
__global__ void convert_x_kernel(const float* __restrict__ x,
                                 unsigned short* __restrict__ xf) {
    int t = blockIdx.x * blockDim.x + threadIdx.x;   // 0..131071
    int chunk = t >> 6;
    int lane  = t & 63;
    int ktile = chunk >> 4;
    int mtile = chunk & 15;
    int m = mtile * 16 + (lane & 15);
    int k = ktile * 32 + ((lane >> 4) << 3);
    const float* xp = x + (size_t)m * K_DIM + k;
    float4 lo = *(const float4*)xp;
    float4 hi = *(const float4*)(xp + 4);
    union { unsigned short s[8]; int4 v; } o;
    o.s[0] = f2bf(lo.x); o.s[1] = f2bf(lo.y); o.s[2] = f2bf(lo.z); o.s[3] = f2bf(lo.w);
    o.s[4] = f2bf(hi.x); o.s[5] = f2bf(hi.y); o.s[6] = f2bf(hi.z); o.s[7] = f2bf(hi.w);
    *(int4*)(xf + ((size_t)t << 3)) = o.v;
}

// v3: grid = N/BN = 448 blocks, 512 threads = 8 waves. Full M=256 x BN=32.
// ALL steady-state VMEM is global_load_lds -> counted vmcnt(1) per iter,
// barriers never drain the pipeline. A double-buffered (1-iter slack);
// raw q depth-3 rotation (2-iter slack); dequant LDS->LDS once per element.
__global__ __launch_bounds__(512, 1)
void plq_gemm_v3(const unsigned short* __restrict__ xf,
                 const int* __restrict__ q,
                 const float* __restrict__ qs,
                 const float* __restrict__ qb,
                 const float* __restrict__ bias,
                 float* __restrict__ out)
{
    __shared__ unsigned short Ab[2][16384];   // 2 x 32 KB bf16 A-tiles (fragment order)
    __shared__ int            rq[3][2048];    // 3 x 8 KB raw q tiles [64k][32n]
    __shared__ unsigned short wb[2][BN * RS]; // 2 x 5 KB dequantized w [n][k+pad]
    __shared__ float          scb[32 * BN];   // scales  [group][n] 4 KB
    __shared__ float          zbb[32 * BN];   // zeros   [group][n] 4 KB

    const int tid  = threadIdx.x;
    const int lane = tid & 63;
    const int wv   = tid >> 6;          // wave 0..7
    const int n0   = blockIdx.x * BN;

    // dequant partition: thread -> (n, 4 consecutive k)
    const int dq_n  = tid & 31;
    const int dq_k0 = (tid >> 5) * 4;   // 0..60

    auto issueA = [&](int t, int p) {   // A tile t -> Ab[p]; 4 glds/wave
        const char* src = (const char*)xf + (size_t)t * 32768 + wv * 4096 + (lane << 4);
        char* dst = (char*)&Ab[p][0] + wv * 4096;
        glds16(src,        dst);
        glds16(src + 1024, dst + 1024);
        glds16(src + 2048, dst + 2048);
        glds16(src + 3072, dst + 3072);
    };
    auto issueQ = [&](int t) {          // raw q tile t -> rq[t%3]; 1 glds/wave
        const int* src = q + (size_t)(t * BK + wv * 8 + (lane >> 3)) * N_DIM
                           + n0 + ((lane & 7) << 2);
        char* dst = (char*)&rq[t % 3][0] + wv * 1024;
        glds16(src, dst);
    };
    auto dequant = [&](int t, unsigned short* dstw) {
        const int* rp = &rq[t % 3][0];
        const int g = t >> 1;           // BK=64: group = t/2
        float s = scb[g * BN + dq_n];
        float z = zbb[g * BN + dq_n];
        int v0 = rp[(dq_k0 + 0) * 32 + dq_n];
        int v1 = rp[(dq_k0 + 1) * 32 + dq_n];
        int v2 = rp[(dq_k0 + 2) * 32 + dq_n];
        int v3 = rp[(dq_k0 + 3) * 32 + dq_n];
        float f0 = (float)v0 * s + z;
        float f1 = (float)v1 * s + z;
        float f2 = (float)v2 * s + z;
        float f3 = (float)v3 * s + z;
        union { unsigned u[2]; double d; } pk;
        pk.u[0] = (unsigned)f2bf(f0) | ((unsigned)f2bf(f1) << 16);
        pk.u[1] = (unsigned)f2bf(f2) | ((unsigned)f2bf(f3) << 16);
        *(double*)&dstw[dq_n * RS + dq_k0] = pk.d;     // ds_write_b64
    };

    f32x4 acc[2][2] = {};
    auto compute = [&](int p) {
        const unsigned short* ab = &Ab[p][0];
        const unsigned short* bb = &wb[p][0];
        #pragma unroll
        for (int ks = 0; ks < 2; ++ks) {
            const int kb = ks * 32 + ((lane >> 4) << 3);
            short8 b0 = *(const short8*)&bb[(     (lane & 15)) * RS + kb];
            short8 b1 = *(const short8*)&bb[(16 + (lane & 15)) * RS + kb];
            short8 a0 = *(const short8*)&ab[(ks * 16 + 2 * wv + 0) * 512 + (lane << 3)];
            short8 a1 = *(const short8*)&ab[(ks * 16 + 2 * wv + 1) * 512 + (lane << 3)];
            acc[0][0] = __builtin_amdgcn_mfma_f32_16x16x32_bf16(a0, b0, acc[0][0], 0, 0, 0);
            acc[0][1] = __builtin_amdgcn_mfma_f32_16x16x32_bf16(a0, b1, acc[0][1], 0, 0, 0);
            acc[1][0] = __builtin_amdgcn_mfma_f32_16x16x32_bf16(a1, b0, acc[1][0], 0, 0, 0);
            acc[1][1] = __builtin_amdgcn_mfma_f32_16x16x32_bf16(a1, b1, acc[1][1], 0, 0, 0);
        }
    };

    // ---- prologue ----
    {   // scales/zeros -> LDS (one-time; drained before use by compiler waits)
        int g = tid >> 4;
        int c = (tid & 15) * 2;
        float2 s2 = *(const float2*)(qs + (size_t)g * N_DIM + n0 + c);
        float2 z2 = *(const float2*)(qb + (size_t)g * N_DIM + n0 + c);
        *(float2*)&scb[g * BN + c] = s2;
        *(float2*)&zbb[g * BN + c] = z2;
    }
    issueA(0, 0);
    issueQ(0); issueQ(1); issueQ(2);
    asm volatile("s_waitcnt vmcnt(1)" ::: "memory");   // A0,q0,q1 done; q2 in flight
    asm volatile("s_waitcnt lgkmcnt(0)" ::: "memory");
    __builtin_amdgcn_s_barrier();                      // scb/zbb + rq0 visible
    dequant(0, &wb[0][0]);
    asm volatile("s_waitcnt lgkmcnt(0)" ::: "memory");
    __builtin_amdgcn_s_barrier();                      // wb[0] visible

    // ---- main loop ----
    #pragma unroll 1
    for (int i = 0; i < NITER; ++i) {
        const int p = i & 1;
        if (i + 1 < NITER) issueA(i + 1, p ^ 1);       // 4 glds (1-iter slack)
        if (i + 3 < NITER) issueQ(i + 3);              // 1 glds (2-iter slack)
        compute(p);                                    // 8 ds_read_b128 + 8 MFMA
        if (i + 1 < NITER) dequant(i + 1, &wb[p ^ 1][0]);
        // drain q(i+2) + A(i+1) (oldest 5), keep q(i+3) in flight
        if (i + 3 < NITER) asm volatile("s_waitcnt vmcnt(1)" ::: "memory");
        else               asm volatile("s_waitcnt vmcnt(0)" ::: "memory");
        asm volatile("s_waitcnt lgkmcnt(0)" ::: "memory");
        __builtin_amdgcn_s_barrier();
    }

    // ---- epilogue: C/D layout col = lane&15, row = (lane>>4)*4 + r ----
    #pragma unroll
    for (int nf = 0; nf < 2; ++nf) {
        const int n = n0 + nf * 16 + (lane & 15);
        const float bb2 = bias[n];
        #pragma unroll
        for (int mf = 0; mf < 2; ++mf) {
            const int m0 = wv * 32 + mf * 16 + ((lane >> 4) << 2);
            #pragma unroll
            for (int r = 0; r < 4; ++r)
                out[(size_t)(m0 + r) * N_DIM + n] = acc[mf][nf][r] + bb2;
        }
    }
}

// ---------------- fallback (no workspace): round-1 kernel, A from global ----
#define FBN 64
#define FBK 128
#define FNITER 32
#define FRS 136
__global__ __launch_bounds__(512, 2)
void plq_gemm_fb(const float* __restrict__ x,
                 const int* __restrict__ q,
                 const float* __restrict__ qs,
                 const float* __restrict__ qb,
                 const float* __restrict__ bias,
                 float* __restrict__ out)
{
    __shared__ unsigned short wlds[2][FBN * FRS];
    const int tid  = threadIdx.x;
    const int lane = tid & 63;
    const int wv   = tid >> 6;
    const int wm   = wv >> 1;
    const int wn   = wv & 1;
    const int n0   = blockIdx.x * FBN;
    const int nl = (tid & 31) * 2;
    const int kl = (tid >> 5) * 8;

    f32x4 acc[4][2] = {};
    int2   qr[8];
    float2 sv, zv;

    auto loadq = [&](int i) {
        const int* qp = q + (size_t)(i * FBK + kl) * N_DIM + (n0 + nl);
        #pragma unroll
        for (int j = 0; j < 8; ++j) qr[j] = *(const int2*)(qp + (size_t)j * N_DIM);
        sv = *(const float2*)(qs + (size_t)i * N_DIM + (n0 + nl));
        zv = *(const float2*)(qb + (size_t)i * N_DIM + (n0 + nl));
    };
    auto deqw = [&](int b) {
        union { unsigned u[4]; int4 v; } p0, p1;
        #pragma unroll
        for (int j = 0; j < 4; ++j) {
            float a0 = (float)qr[2*j].x   * sv.x + zv.x;
            float a1 = (float)qr[2*j+1].x * sv.x + zv.x;
            float c0 = (float)qr[2*j].y   * sv.y + zv.y;
            float c1 = (float)qr[2*j+1].y * sv.y + zv.y;
            p0.u[j] = (unsigned)f2bf(a0) | ((unsigned)f2bf(a1) << 16);
            p1.u[j] = (unsigned)f2bf(c0) | ((unsigned)f2bf(c1) << 16);
        }
        *(int4*)&wlds[b][(nl + 0) * FRS + kl] = p0.v;
        *(int4*)&wlds[b][(nl + 1) * FRS + kl] = p1.v;
    };
    auto compute = [&](int i, int cur) {
        short8 afr[4][4];
        #pragma unroll
        for (int ks = 0; ks < 4; ++ks)
            #pragma unroll
            for (int mf = 0; mf < 4; ++mf) {
                int m = wm * 64 + mf * 16 + (lane & 15);
                int k = i * FBK + ks * 32 + ((lane >> 4) << 3);
                const float* xp = x + (size_t)m * K_DIM + k;
                float4 lo = *(const float4*)xp;
                float4 hi = *(const float4*)(xp + 4);
                union { unsigned short s[8]; short8 v; } u;
                u.s[0] = f2bf(lo.x); u.s[1] = f2bf(lo.y); u.s[2] = f2bf(lo.z); u.s[3] = f2bf(lo.w);
                u.s[4] = f2bf(hi.x); u.s[5] = f2bf(hi.y); u.s[6] = f2bf(hi.z); u.s[7] = f2bf(hi.w);
                afr[ks][mf] = u.v;
            }
        #pragma unroll
        for (int ks = 0; ks < 4; ++ks) {
            const int kb = ks * 32 + ((lane >> 4) << 3);
            short8 b0 = *(const short8*)&wlds[cur][(wn * 32 +      (lane & 15)) * FRS + kb];
            short8 b1 = *(const short8*)&wlds[cur][(wn * 32 + 16 + (lane & 15)) * FRS + kb];
            #pragma unroll
            for (int mf = 0; mf < 4; ++mf) {
                acc[mf][0] = __builtin_amdgcn_mfma_f32_16x16x32_bf16(afr[ks][mf], b0, acc[mf][0], 0, 0, 0);
                acc[mf][1] = __builtin_amdgcn_mfma_f32_16x16x32_bf16(afr[ks][mf], b1, acc[mf][1], 0, 0, 0);
            }
        }
    };

    loadq(0); deqw(0); __syncthreads();
    for (int i = 0; i < FNITER; ++i) {
        const int cur = i & 1;
        if (i + 1 < FNITER) loadq(i + 1);
        compute(i, cur);
        if (i + 1 < FNITER) deqw(cur ^ 1);
        __syncthreads();
    }
    #pragma unroll
    for (int nf = 0; nf < 2; ++nf) {
        const int n = n0 + wn * 32 + nf * 16 + (lane & 15);
        const float bb = bias[n];
        #pragma unroll
        for (int mf = 0; mf < 4; ++mf) {
            const int m0 = wm * 64 + mf * 16 + ((lane >> 4) << 2);
            #pragma unroll
            for (int r = 0; r < 4; ++r)
                out[(size_t)(m0 + r) * N_DIM + n] = acc[mf][nf][r] + bb;
        }
    }
}

extern "C" void kernel_launch(void* const* d_in, const int* in_sizes, int n_in,
                              void* d_out, int out_size, void* d_ws, size_t ws_size,
                              hipStream_t stream) {
    const float* x    = (const float*)d_in[0];
    const int*   qk   = (const int*)d_in[1];
    const float* qs   = (const float*)d_in[2];
    const float* qb   = (const float*)d_in[3];
    const float* bias = (const float*)d_in[4];
    float* out = (float*)d_out;

    const size_t xf_bytes = (size_t)M_DIM * K_DIM * sizeof(unsigned short);
    if (ws_size >= xf_bytes) {
        unsigned short* xf = (unsigned short*)d_ws;
        convert_x_kernel<<<512, 256, 0, stream>>>(x, xf);
        plq_gemm_v3<<<N_DIM / BN, 512, 0, stream>>>(xf, qk, qs, qb, bias, out);
    } else {
        plq_gemm_fb<<<N_DIM / FBN, 512, 0, stream>>>(x, qk, qs, qb, bias, out);
    }
}

// Round 4
// 111.871 us; speedup vs baseline: 1.4078x; 1.4078x over previous
//
#include <hip/hip_runtime.h>
#include <hip/hip_bf16.h>

// Problem constants
#define K_DIM 4096
#define N_DIM 14336
#define M_DIM 256
#define BM 128
#define BN 32
#define BK 64
#define NITER 64        // K_DIM / BK
#define RS 72           // wb row stride in shorts (144 B rows, 16B aligned, 2-way banks = free)

typedef __attribute__((ext_vector_type(4))) float f32x4;
typedef __attribute__((ext_vector_type(8))) short short8;

__device__ __forceinline__ unsigned short f2bf(float f) {
    union { float f; unsigned u; } v; v.f = f;
    unsigned r = v.u + 0x7fffu + ((v.u >> 16) & 1u);   // RNE
    return (unsigned short)(r >> 16);
}

// Pre-convert x (fp32 [256][4096]) into bf16 MFMA-A-fragment order:
// chunk = ktile*16 + mtile (ktile=k/32, mtile=m/16); lane l of chunk holds
// 8 bf16 = x[mtile*16 + (l&15)][ktile*32 + (l>>4)*8 .. +8]
__global__ void convert_x_kernel(const float* __restrict__ x,
                                 unsigned short* __restrict__ xf) {
    int t = blockIdx.x * blockDim.x + threadIdx.x;   // 0..131071
    int chunk = t >> 6;
    int lane  = t & 63;
    int ktile = chunk >> 4;
    int mtile = chunk & 15;
    int m = mtile * 16 + (lane & 15);
    int k = ktile * 32 + ((lane >> 4) << 3);
    const float* xp = x + (size_t)m * K_DIM + k;
    float4 lo = *(const float4*)xp;
    float4 hi = *(const float4*)(xp + 4);
    union { unsigned short s[8]; int4 v; } o;
    o.s[0] = f2bf(lo.x); o.s[1] = f2bf(lo.y); o.s[2] = f2bf(lo.z); o.s[3] = f2bf(lo.w);
    o.s[4] = f2bf(hi.x); o.s[5] = f2bf(hi.y); o.s[6] = f2bf(hi.z); o.s[7] = f2bf(hi.w);
    *(int4*)(xf + ((size_t)t << 3)) = o.v;
}

// v4: TLP-first. 896 blocks x 256 threads (4 waves), LDS 9.2 KB, VGPR<=128
// -> 4 blocks/CU resident (entire grid resident, no tail). q staged
// global->registers depth-2 (static qA/qB sets, unroll-2), dequant ->
// bf16 wb double buffer in LDS, one __syncthreads per K-tile. A-fragments
// load straight from fragment-ordered xf (L2-resident).
template<bool USE_WS>
__global__ __launch_bounds__(256, 4)
void plq_gemm_v4(const float* __restrict__ x,
                 const unsigned short* __restrict__ xf,
                 const int* __restrict__ q,
                 const float* __restrict__ qs,
                 const float* __restrict__ qb,
                 const float* __restrict__ bias,
                 float* __restrict__ out)
{
    __shared__ unsigned short wb0[BN * RS];
    __shared__ unsigned short wb1[BN * RS];

    const int tid  = threadIdx.x;
    const int lane = tid & 63;
    const int wv   = tid >> 6;          // wave 0..3, owns 32 m-rows

    // XCD-contiguous remap (8 XCDs x 112 blocks); m-half fastest so the
    // twin block (same n0, other m-half) is adjacent on the same XCD -> its
    // q read hits L2. q HBM traffic stays ~1x.
    const int bid   = blockIdx.x;
    const int gid   = (bid & 7) * 112 + (bid >> 3);
    const int mhalf = gid & 1;
    const int n0    = (gid >> 1) * BN;
    const int m0b   = mhalf * BM;

    // dequant partition: thread owns 1 n x 8 consecutive k
    const int dq_n  = tid & 31;
    const int dq_k0 = (tid >> 5) << 3;
    const size_t qcol = (size_t)n0 + dq_n;

    f32x4 acc[2][2] = {};

    int   qA[8], qB[8];
    float sA, zA, sB, zB;

    auto loadA = [&](int t) {
        const int* qp = q + (size_t)(t * BK + dq_k0) * N_DIM + qcol;
        #pragma unroll
        for (int j = 0; j < 8; ++j) qA[j] = qp[(size_t)j * N_DIM];
        sA = qs[(size_t)(t >> 1) * N_DIM + qcol];
        zA = qb[(size_t)(t >> 1) * N_DIM + qcol];
    };
    auto loadB = [&](int t) {
        const int* qp = q + (size_t)(t * BK + dq_k0) * N_DIM + qcol;
        #pragma unroll
        for (int j = 0; j < 8; ++j) qB[j] = qp[(size_t)j * N_DIM];
        sB = qs[(size_t)(t >> 1) * N_DIM + qcol];
        zB = qb[(size_t)(t >> 1) * N_DIM + qcol];
    };

    auto deqA = [&]() {
        union { unsigned u[4]; int4 v; } pk;
        #pragma unroll
        for (int j = 0; j < 4; ++j) {
            float f0 = (float)qA[2*j]   * sA + zA;
            float f1 = (float)qA[2*j+1] * sA + zA;
            pk.u[j] = (unsigned)f2bf(f0) | ((unsigned)f2bf(f1) << 16);
        }
        *(int4*)&wb0[dq_n * RS + dq_k0] = pk.v;   // ds_write_b128, 2-way free
    };
    auto deqB = [&]() {
        union { unsigned u[4]; int4 v; } pk;
        #pragma unroll
        for (int j = 0; j < 4; ++j) {
            float f0 = (float)qB[2*j]   * sB + zB;
            float f1 = (float)qB[2*j+1] * sB + zB;
            pk.u[j] = (unsigned)f2bf(f0) | ((unsigned)f2bf(f1) << 16);
        }
        *(int4*)&wb1[dq_n * RS + dq_k0] = pk.v;
    };

    auto compute = [&](int i, const unsigned short* bb) {
        const int mt0 = (mhalf << 3) + (wv << 1);
        #pragma unroll
        for (int ks = 0; ks < 2; ++ks) {
            const int kt = i * 2 + ks;
            short8 a0, a1;
            if (USE_WS) {
                const unsigned short* ap = xf + ((size_t)(kt * 16 + mt0) << 9) + (lane << 3);
                a0 = *(const short8*)ap;
                a1 = *(const short8*)(ap + 512);
            } else {
                const int m = m0b + wv * 32 + (lane & 15);
                const int k = kt * 32 + ((lane >> 4) << 3);
                const float* xp0 = x + (size_t)m * K_DIM + k;
                const float* xp1 = xp0 + (size_t)16 * K_DIM;
                float4 l0 = *(const float4*)xp0, h0 = *(const float4*)(xp0 + 4);
                float4 l1 = *(const float4*)xp1, h1 = *(const float4*)(xp1 + 4);
                union { unsigned short s[8]; short8 v; } u0, u1;
                u0.s[0] = f2bf(l0.x); u0.s[1] = f2bf(l0.y); u0.s[2] = f2bf(l0.z); u0.s[3] = f2bf(l0.w);
                u0.s[4] = f2bf(h0.x); u0.s[5] = f2bf(h0.y); u0.s[6] = f2bf(h0.z); u0.s[7] = f2bf(h0.w);
                u1.s[0] = f2bf(l1.x); u1.s[1] = f2bf(l1.y); u1.s[2] = f2bf(l1.z); u1.s[3] = f2bf(l1.w);
                u1.s[4] = f2bf(h1.x); u1.s[5] = f2bf(h1.y); u1.s[6] = f2bf(h1.z); u1.s[7] = f2bf(h1.w);
                a0 = u0.v; a1 = u1.v;
            }
            const int kb = ks * 32 + ((lane >> 4) << 3);
            short8 b0 = *(const short8*)&bb[(     (lane & 15)) * RS + kb];
            short8 b1 = *(const short8*)&bb[(16 + (lane & 15)) * RS + kb];
            acc[0][0] = __builtin_amdgcn_mfma_f32_16x16x32_bf16(a0, b0, acc[0][0], 0, 0, 0);
            acc[0][1] = __builtin_amdgcn_mfma_f32_16x16x32_bf16(a0, b1, acc[0][1], 0, 0, 0);
            acc[1][0] = __builtin_amdgcn_mfma_f32_16x16x32_bf16(a1, b0, acc[1][0], 0, 0, 0);
            acc[1][1] = __builtin_amdgcn_mfma_f32_16x16x32_bf16(a1, b1, acc[1][1], 0, 0, 0);
        }
    };

    // prologue: tiles 0 and 1 into the two register sets, dequant tile 0
    loadA(0);
    loadB(1);
    deqA();
    __syncthreads();

    // main loop, unroll-2 so qA/qB indexing is static (rule #20)
    #pragma unroll 1
    for (int ii = 0; ii < NITER / 2; ++ii) {
        const int i = 2 * ii;

        if (i + 2 < NITER) loadA(i + 2);    // depth-2: drained at THIS barrier,
        compute(i, wb0);                     // used next iteration -> no stall
        deqB();                              // tile i+1 -> wb1
        __syncthreads();

        if (i + 3 < NITER) loadB(i + 3);
        compute(i + 1, wb1);
        if (i + 2 < NITER) deqA();           // tile i+2 -> wb0
        __syncthreads();
    }

    // epilogue: C/D layout col = lane&15, row = (lane>>4)*4 + r
    #pragma unroll
    for (int nf = 0; nf < 2; ++nf) {
        const int n = n0 + nf * 16 + (lane & 15);
        const float bv = bias[n];
        #pragma unroll
        for (int mf = 0; mf < 2; ++mf) {
            const int m0 = m0b + wv * 32 + mf * 16 + ((lane >> 4) << 2);
            #pragma unroll
            for (int r = 0; r < 4; ++r)
                out[(size_t)(m0 + r) * N_DIM + n] = acc[mf][nf][r] + bv;
        }
    }
}

extern "C" void kernel_launch(void* const* d_in, const int* in_sizes, int n_in,
                              void* d_out, int out_size, void* d_ws, size_t ws_size,
                              hipStream_t stream) {
    const float* x    = (const float*)d_in[0];
    const int*   qk   = (const int*)d_in[1];
    const float* qs   = (const float*)d_in[2];
    const float* qb   = (const float*)d_in[3];
    const float* bias = (const float*)d_in[4];
    float* out = (float*)d_out;

    const int grid = (M_DIM / BM) * (N_DIM / BN);   // 2 * 448 = 896
    const size_t xf_bytes = (size_t)M_DIM * K_DIM * sizeof(unsigned short);
    if (ws_size >= xf_bytes) {
        unsigned short* xf = (unsigned short*)d_ws;
        convert_x_kernel<<<512, 256, 0, stream>>>(x, xf);
        plq_gemm_v4<true><<<grid, 256, 0, stream>>>(x, xf, qk, qs, qb, bias, out);
    } else {
        plq_gemm_v4<false><<<grid, 256, 0, stream>>>(x, nullptr, qk, qs, qb, bias, out);
    }
}

// Round 5
// 99.650 us; speedup vs baseline: 1.5804x; 1.1226x over previous
//
#include <hip/hip_runtime.h>
#include <hip/hip_bf16.h>

// Problem constants
#define K_DIM 4096
#define N_DIM 14336
#define M_DIM 256
#define BN 128          // block n-width
#define BK 32           // k per iter per k-half
#define NIT 64          // 2048 / 32 iterations per k-half
#define KHALF 2048      // internal split-K=2

typedef __attribute__((ext_vector_type(4))) float f32x4;
typedef __attribute__((ext_vector_type(8))) short short8;

__device__ __forceinline__ unsigned short f2bf(float f) {
    union { float f; unsigned u; } v; v.f = f;
    unsigned r = v.u + 0x7fffu + ((v.u >> 16) & 1u);   // RNE
    return (unsigned short)(r >> 16);
}

__device__ __forceinline__ void glds16(const void* g, void* l) {
    __builtin_amdgcn_global_load_lds(
        (const __attribute__((address_space(1))) void*)g,
        (__attribute__((address_space(3))) void*)l, 16, 0, 0);
}

// counted-vmcnt barrier: drains A-glds, keeps the q register prefetch flying
#define KBAR(N) do { \
    asm volatile("s_waitcnt vmcnt(" #N ")" ::: "memory"); \
    asm volatile("s_waitcnt lgkmcnt(0)" ::: "memory");    \
    __builtin_amdgcn_s_barrier();                          \
} while (0)

// Pre-convert x (fp32 [256][4096]) into bf16 MFMA-A-fragment order:
// chunk = ktile*16 + mtile; lane l holds x[mtile*16+(l&15)][ktile*32+(l>>4)*8 ..+8]
__global__ void convert_x_kernel(const float* __restrict__ x,
                                 unsigned short* __restrict__ xf) {
    int t = blockIdx.x * blockDim.x + threadIdx.x;   // 0..131071
    int chunk = t >> 6;
    int lane  = t & 63;
    int ktile = chunk >> 4;
    int mtile = chunk & 15;
    int m = mtile * 16 + (lane & 15);
    int k = ktile * 32 + ((lane >> 4) << 3);
    const float* xp = x + (size_t)m * K_DIM + k;
    float4 lo = *(const float4*)xp;
    float4 hi = *(const float4*)(xp + 4);
    union { unsigned short s[8]; int4 v; } o;
    o.s[0] = f2bf(lo.x); o.s[1] = f2bf(lo.y); o.s[2] = f2bf(lo.z); o.s[3] = f2bf(lo.w);
    o.s[4] = f2bf(hi.x); o.s[5] = f2bf(hi.y); o.s[6] = f2bf(hi.z); o.s[7] = f2bf(hi.w);
    *(int4*)(xf + ((size_t)t << 3)) = o.v;
}

// v6: 224 blocks x 512 thr (8 waves = 2m x 2n x 2k), one block per CU.
// A via global_load_lds (fragment-ordered xf, linear, conflict-free),
// q via 2 static register sets (unroll-2, deep ILP), dequant -> ds_write W,
// counted vmcnt(18) barriers (q prefetch never drains), in-LDS split-K reduce.
__global__ __launch_bounds__(512, 2)
void plq_gemm_v6(const unsigned short* __restrict__ xf,
                 const int* __restrict__ q,
                 const float* __restrict__ qs,
                 const float* __restrict__ qb,
                 const float* __restrict__ bias,
                 float* __restrict__ out)
{
    __shared__ char smem[65536];   // [0,32K): A dbuf 2x16KB ; [32K,64K): W dbuf 2x16KB

    const int tid  = threadIdx.x;
    const int lane = tid & 63;
    const int wv   = tid >> 6;

    // compute roles: 2m x 2n x 2k
    const int kh = wv & 1;
    const int wn = (wv >> 1) & 1;
    const int wm = wv >> 2;

    // XCD-chunked grid: twin m-halves (same n0) adjacent on same XCD -> q L2 hit
    const int gid = ((blockIdx.x & 7) * 28) + (blockIdx.x >> 3);   // 224 = 8*28
    const int mh  = gid & 1;
    const int n0  = (gid >> 1) * BN;

    // dequant roles: thread -> col n_d, k-half kh_d, k-strips g8 and g8+16
    const int n_d  = ((wv & 1) << 6) + lane;        // 0..127
    const int kh_d = (wv >> 1) & 1;
    const int g8   = ((wv >> 2) & 1) << 3;          // 0 or 8

    f32x4 acc[4][4] = {};

    int   qA[16], qB[16];
    float sA, zA, sB, zB;

    auto issueA = [&](int t, int pb) {   // 16 KB fragment-ordered tile, 2 glds/thread
        #pragma unroll
        for (int j = 0; j < 2; ++j) {
            const int flat = (wv << 11) + (j << 10) + (lane << 4);   // 0..16383
            const int kh2  = flat >> 13;
            const int off  = flat & 8191;
            const char* src = (const char*)xf
                + (((size_t)((((kh2 << 6) + t) << 4) + (mh << 3))) << 10) + off;
            glds16(src, smem + (pb << 14) + flat);
        }
    };

    auto issueQA = [&](int t) {          // 16 dword + scale/zero, all -> registers
        const int* base = q + (size_t)(kh_d * KHALF + t * BK) * N_DIM + n0 + n_d;
        #pragma unroll
        for (int st = 0; st < 2; ++st)
            #pragma unroll
            for (int j = 0; j < 8; ++j)
                qA[st * 8 + j] = base[(size_t)(g8 + st * 16 + j) * N_DIM];
        const int g = (kh_d << 4) + (t >> 2);
        sA = qs[(size_t)g * N_DIM + n0 + n_d];
        zA = qb[(size_t)g * N_DIM + n0 + n_d];
    };
    auto issueQB = [&](int t) {
        const int* base = q + (size_t)(kh_d * KHALF + t * BK) * N_DIM + n0 + n_d;
        #pragma unroll
        for (int st = 0; st < 2; ++st)
            #pragma unroll
            for (int j = 0; j < 8; ++j)
                qB[st * 8 + j] = base[(size_t)(g8 + st * 16 + j) * N_DIM];
        const int g = (kh_d << 4) + (t >> 2);
        sB = qs[(size_t)g * N_DIM + n0 + n_d];
        zB = qb[(size_t)g * N_DIM + n0 + n_d];
    };

    auto deqA_ = [&](int pb) {           // tile in qA -> W buf pb (2 x ds_write_b128)
        char* wbase = smem + 32768 + (pb << 14) + (kh_d << 13) + n_d * 64 + (g8 << 1);
        #pragma unroll
        for (int st = 0; st < 2; ++st) {
            union { unsigned u[4]; int4 v; } pk;
            #pragma unroll
            for (int j = 0; j < 4; ++j) {
                float f0 = (float)qA[st * 8 + 2 * j]     * sA + zA;
                float f1 = (float)qA[st * 8 + 2 * j + 1] * sA + zA;
                pk.u[j] = (unsigned)f2bf(f0) | ((unsigned)f2bf(f1) << 16);
            }
            *(int4*)(wbase + (st << 5)) = pk.v;
        }
    };
    auto deqB_ = [&](int pb) {
        char* wbase = smem + 32768 + (pb << 14) + (kh_d << 13) + n_d * 64 + (g8 << 1);
        #pragma unroll
        for (int st = 0; st < 2; ++st) {
            union { unsigned u[4]; int4 v; } pk;
            #pragma unroll
            for (int j = 0; j < 4; ++j) {
                float f0 = (float)qB[st * 8 + 2 * j]     * sB + zB;
                float f1 = (float)qB[st * 8 + 2 * j + 1] * sB + zB;
                pk.u[j] = (unsigned)f2bf(f0) | ((unsigned)f2bf(f1) << 16);
            }
            *(int4*)(wbase + (st << 5)) = pk.v;
        }
    };

    auto compute = [&](int pb) {         // 8 ds_read_b128 + 16 MFMA
        const char* abase = smem + (pb << 14) + (kh << 13) + (wm << 12) + (lane << 4);
        const char* bbase = smem + 32768 + (pb << 14) + (kh << 13)
                          + (((wn << 6) + (lane & 15)) << 6) + ((lane >> 4) << 4);
        short8 af[4], bf[4];
        #pragma unroll
        for (int mf = 0; mf < 4; ++mf)
            af[mf] = *(const short8*)(abase + (mf << 10));
        #pragma unroll
        for (int nf = 0; nf < 4; ++nf)
            bf[nf] = *(const short8*)(bbase + (nf << 10));
        #pragma unroll
        for (int mf = 0; mf < 4; ++mf)
            #pragma unroll
            for (int nf = 0; nf < 4; ++nf)
                acc[mf][nf] = __builtin_amdgcn_mfma_f32_16x16x32_bf16(
                                  af[mf], bf[nf], acc[mf][nf], 0, 0, 0);
    };

    // ---- prologue ----
    issueQA(0);            // 18 outstanding
    issueQB(1);            // 36
    issueA(0, 0);          // 38
    deqA_(0);              // compiler waits vmcnt(20): drains qA(0) only
    KBAR(0);               // one-time full drain; A0 + W0 visible

    // ---- main loop: 31 x 2 iterations, fully static set rotation ----
    #pragma unroll 1
    for (int ii = 0; ii < 31; ++ii) {
        const int i = ii << 1;

        issueA(i + 1, 1);          // 2 glds (oldest)
        issueQA(i + 2);            // 18 reg-loads (kept in flight)
        deqB_(1);                  // tile i+1 -> W buf1 (waits old qB only)
        compute(0);                // tile i
        KBAR(18);                  // drain A(i+1), keep qA(i+2)

        issueA(i + 2, 0);
        issueQB(i + 3);
        deqA_(0);                  // tile i+2 -> W buf0
        compute(1);                // tile i+1
        KBAR(18);
    }
    // ---- tail: i = 62, 63 ----
    issueA(63, 1);
    deqB_(1);                      // tile 63 (qB filled at i=61)
    compute(0);                    // tile 62
    KBAR(0);
    compute(1);                    // tile 63
    asm volatile("s_waitcnt lgkmcnt(0)" ::: "memory");
    __builtin_amdgcn_s_barrier();

    // ---- split-K reduction via LDS (deterministic) + bias + store ----
    if (kh == 1) {
        char* rb = smem + ((wv >> 1) << 14) + (lane << 4);
        #pragma unroll
        for (int mf = 0; mf < 4; ++mf)
            #pragma unroll
            for (int nf = 0; nf < 4; ++nf)
                *(f32x4*)(rb + (((mf << 2) + nf) << 10)) = acc[mf][nf];
    }
    asm volatile("s_waitcnt lgkmcnt(0)" ::: "memory");
    __builtin_amdgcn_s_barrier();
    if (kh == 0) {
        const char* rb = smem + ((wv >> 1) << 14) + (lane << 4);
        #pragma unroll
        for (int nf = 0; nf < 4; ++nf) {
            const int n = n0 + (wn << 6) + (nf << 4) + (lane & 15);
            const float bv = bias[n];
            #pragma unroll
            for (int mf = 0; mf < 4; ++mf) {
                f32x4 o = acc[mf][nf] + *(const f32x4*)(rb + (((mf << 2) + nf) << 10));
                const int m0 = (mh << 7) + (wm << 6) + (mf << 4) + ((lane >> 4) << 2);
                #pragma unroll
                for (int r = 0; r < 4; ++r)
                    out[(size_t)(m0 + r) * N_DIM + n] = o[r] + bv;
            }
        }
    }
}

// ---------------- fallback (no workspace): round-1 structure ----
#define FBN 64
#define FBK 128
#define FNITER 32
#define FRS 136
__global__ __launch_bounds__(512, 2)
void plq_gemm_fb(const float* __restrict__ x,
                 const int* __restrict__ q,
                 const float* __restrict__ qs,
                 const float* __restrict__ qb,
                 const float* __restrict__ bias,
                 float* __restrict__ out)
{
    __shared__ unsigned short wlds[2][FBN * FRS];
    const int tid  = threadIdx.x;
    const int lane = tid & 63;
    const int wv   = tid >> 6;
    const int wm   = wv >> 1;
    const int wn   = wv & 1;
    const int n0   = blockIdx.x * FBN;
    const int nl = (tid & 31) * 2;
    const int kl = (tid >> 5) * 8;

    f32x4 acc[4][2] = {};
    int2   qr[8];
    float2 sv, zv;

    auto loadq = [&](int i) {
        const int* qp = q + (size_t)(i * FBK + kl) * N_DIM + (n0 + nl);
        #pragma unroll
        for (int j = 0; j < 8; ++j) qr[j] = *(const int2*)(qp + (size_t)j * N_DIM);
        sv = *(const float2*)(qs + (size_t)i * N_DIM + (n0 + nl));
        zv = *(const float2*)(qb + (size_t)i * N_DIM + (n0 + nl));
    };
    auto deqw = [&](int b) {
        union { unsigned u[4]; int4 v; } p0, p1;
        #pragma unroll
        for (int j = 0; j < 4; ++j) {
            float a0 = (float)qr[2*j].x   * sv.x + zv.x;
            float a1 = (float)qr[2*j+1].x * sv.x + zv.x;
            float c0 = (float)qr[2*j].y   * sv.y + zv.y;
            float c1 = (float)qr[2*j+1].y * sv.y + zv.y;
            p0.u[j] = (unsigned)f2bf(a0) | ((unsigned)f2bf(a1) << 16);
            p1.u[j] = (unsigned)f2bf(c0) | ((unsigned)f2bf(c1) << 16);
        }
        *(int4*)&wlds[b][(nl + 0) * FRS + kl] = p0.v;
        *(int4*)&wlds[b][(nl + 1) * FRS + kl] = p1.v;
    };
    auto compute = [&](int i, int cur) {
        short8 afr[4][4];
        #pragma unroll
        for (int ks = 0; ks < 4; ++ks)
            #pragma unroll
            for (int mf = 0; mf < 4; ++mf) {
                int m = wm * 64 + mf * 16 + (lane & 15);
                int k = i * FBK + ks * 32 + ((lane >> 4) << 3);
                const float* xp = x + (size_t)m * K_DIM + k;
                float4 lo = *(const float4*)xp;
                float4 hi = *(const float4*)(xp + 4);
                union { unsigned short s[8]; short8 v; } u;
                u.s[0] = f2bf(lo.x); u.s[1] = f2bf(lo.y); u.s[2] = f2bf(lo.z); u.s[3] = f2bf(lo.w);
                u.s[4] = f2bf(hi.x); u.s[5] = f2bf(hi.y); u.s[6] = f2bf(hi.z); u.s[7] = f2bf(hi.w);
                afr[ks][mf] = u.v;
            }
        #pragma unroll
        for (int ks = 0; ks < 4; ++ks) {
            const int kb = ks * 32 + ((lane >> 4) << 3);
            short8 b0 = *(const short8*)&wlds[cur][(wn * 32 +      (lane & 15)) * FRS + kb];
            short8 b1 = *(const short8*)&wlds[cur][(wn * 32 + 16 + (lane & 15)) * FRS + kb];
            #pragma unroll
            for (int mf = 0; mf < 4; ++mf) {
                acc[mf][0] = __builtin_amdgcn_mfma_f32_16x16x32_bf16(afr[ks][mf], b0, acc[mf][0], 0, 0, 0);
                acc[mf][1] = __builtin_amdgcn_mfma_f32_16x16x32_bf16(afr[ks][mf], b1, acc[mf][1], 0, 0, 0);
            }
        }
    };

    loadq(0); deqw(0); __syncthreads();
    for (int i = 0; i < FNITER; ++i) {
        const int cur = i & 1;
        if (i + 1 < FNITER) loadq(i + 1);
        compute(i, cur);
        if (i + 1 < FNITER) deqw(cur ^ 1);
        __syncthreads();
    }
    #pragma unroll
    for (int nf = 0; nf < 2; ++nf) {
        const int n = n0 + wn * 32 + nf * 16 + (lane & 15);
        const float bb = bias[n];
        #pragma unroll
        for (int mf = 0; mf < 4; ++mf) {
            const int m0 = wm * 64 + mf * 16 + ((lane >> 4) << 2);
            #pragma unroll
            for (int r = 0; r < 4; ++r)
                out[(size_t)(m0 + r) * N_DIM + n] = acc[mf][nf][r] + bb;
        }
    }
}

extern "C" void kernel_launch(void* const* d_in, const int* in_sizes, int n_in,
                              void* d_out, int out_size, void* d_ws, size_t ws_size,
                              hipStream_t stream) {
    const float* x    = (const float*)d_in[0];
    const int*   qk   = (const int*)d_in[1];
    const float* qs   = (const float*)d_in[2];
    const float* qb   = (const float*)d_in[3];
    const float* bias = (const float*)d_in[4];
    float* out = (float*)d_out;

    const size_t xf_bytes = (size_t)M_DIM * K_DIM * sizeof(unsigned short);
    if (ws_size >= xf_bytes) {
        unsigned short* xf = (unsigned short*)d_ws;
        convert_x_kernel<<<512, 256, 0, stream>>>(x, xf);
        plq_gemm_v6<<<(N_DIM / BN) * 2, 512, 0, stream>>>(xf, qk, qs, qb, bias, out);
    } else {
        plq_gemm_fb<<<N_DIM / FBN, 512, 0, stream>>>(x, qk, qs, qb, bias, out);
    }
}